// Round 13
// baseline (90.846 us; speedup 1.0000x reference)
//
#include <hip/hip_runtime.h>

// LocalCrossCorrelation3D: I,J (2,1,96,192,192) fp32 -> (loss[2], cc[2,81,192,192])
// Window (16,9,9): depth valid (96->81), h/w zero-padded +-4.
// K1 = depth sliding sum (regs, prefetched) + two-stage 3+3 w-box in float4
// LDS, two od-outputs per barrier round, raw barriers (vmcnt never drained).
// ws = SoA: 3 u32 planes (bf16 pairs), perfectly coalesced stores/loads.
// K2 = h sliding box, full unroll + static ring, CH=12 for occupancy.

constexpr int N = 2, D = 96, H = 192, W = 192;
constexpr int OD = 81;            // D - 16 + 1
constexpr int KD = 16;
constexpr int HWp = H * W;        // 36864
constexpr float INV_WIN = 1.0f / 1296.0f;
constexpr float EPS_NZ = 3.0590232050182579e-07f;  // e^-15
constexpr int CH = 12;            // h-chunk per block in K2 (192/12 = 16)
constexpr int ODPB = 14;          // od-range per K1 block (9 blocks/CU)

__device__ __forceinline__ unsigned bf16rne(float f) {  // f32 -> bf16 bits (RNE)
  unsigned u = __float_as_uint(f);
  return (u + 0x7fffu + ((u >> 16) & 1u)) >> 16;
}
__device__ __forceinline__ float bf16tof(unsigned h) {  // bf16 bits -> f32
  return __uint_as_float(h << 16);
}

// ---------------------------------------------------------------------------
// K1. Per (n,h) row, stream depth with running 5-ch sums; snapshots for od
// and od+1 go to LDS buffer sets 0/1; one {B1,stage1x2,B2,stage2x2} round
// serves both. Entering/leaving slices for the NEXT pair prefetched during
// the current round. ws planes: [3][n][odi][h][w] u32 (bf16 pairs:
// plane0=(s0,s1), plane1=(s2,s3), plane2=(s4,_)), plane stride PS.
__global__ __launch_bounds__(192)
void k_dw(const float* __restrict__ I, const float* __restrict__ J,
          unsigned* __restrict__ ws, int od0, int c, int odcStride) {
  const int h = blockIdx.x;
  const int n = blockIdx.z;
  const int os = od0 + blockIdx.y * ODPB;
  int oe = od0 + c; if (os + ODPB < oe) oe = os + ODPB;
  if (os >= oe) return;
  const int w = threadIdx.x;

  __shared__ float4 x4[2][W + 8];
  __shared__ float  x1[2][W + 8];
  __shared__ float4 a4[2][W + 8];
  __shared__ float  a1[2][W + 8];

  if (w < 4) {
    x4[0][w] = make_float4(0.f,0.f,0.f,0.f); x1[0][w] = 0.f;
    x4[1][w] = make_float4(0.f,0.f,0.f,0.f); x1[1][w] = 0.f;
  }
  if (w >= W - 4) {
    x4[0][w + 8] = make_float4(0.f,0.f,0.f,0.f); x1[0][w + 8] = 0.f;
    x4[1][w + 8] = make_float4(0.f,0.f,0.f,0.f); x1[1][w + 8] = 0.f;
  }
  __syncthreads();   // one safe barrier before the pipelined loop

  const size_t colBase = ((size_t)n * D * H + h) * (size_t)W + w;
  const float* Ip = I + colBase;
  const float* Jp = J + colBase;
  const size_t PS = (size_t)2 * odcStride * HWp;    // plane stride (u32)
  unsigned* wp0 = ws + ((size_t)n * odcStride) * HWp + (size_t)h * W + w;
  unsigned* wp1 = wp0 + PS;
  unsigned* wp2 = wp0 + 2 * PS;

  // extra a3 position for halo coverage (pe in 1..3 and 196..198)
  int pe = -1;
  if (w < 3) pe = w + 1;
  else if (w >= W - 3) pe = w + 7;
  const int p = 4 + w;

  // warm-up: accumulate slices [os, os+KD-2] (15 slices)
  float sI = 0.f, sJ = 0.f, sII = 0.f, sJJ = 0.f, sIJ = 0.f;
  for (int d = os; d < os + KD - 1; ++d) {
    const float iv = Ip[(size_t)d * HWp];
    const float jv = Jp[(size_t)d * HWp];
    sI += iv; sJ += jv;
    sII += iv * iv; sJJ += jv * jv; sIJ += iv * jv;
  }

  // prefetch first pair: entering od+15 / od+16, leaving od / od+1
  int od = os;
  float eI0 = Ip[(size_t)(od + KD - 1) * HWp];
  float eJ0 = Jp[(size_t)(od + KD - 1) * HWp];
  float lI0 = Ip[(size_t)od * HWp];
  float lJ0 = Jp[(size_t)od * HWp];
  float eI1 = 0.f, eJ1 = 0.f, lI1 = 0.f, lJ1 = 0.f;
  if (od + 1 < oe) {
    eI1 = Ip[(size_t)(od + KD) * HWp];
    eJ1 = Jp[(size_t)(od + KD) * HWp];
    lI1 = Ip[(size_t)(od + 1) * HWp];
    lJ1 = Jp[(size_t)(od + 1) * HWp];
  }

  while (od < oe) {
    const bool two = (od + 1 < oe);
    const float ceI0 = eI0, ceJ0 = eJ0, clI0 = lI0, clJ0 = lJ0;
    const float ceI1 = eI1, ceJ1 = eJ1, clI1 = lI1, clJ1 = lJ1;
    // prefetch next pair (issued now, awaited next iteration)
    const int odn = od + 2;
    if (odn < oe) {
      eI0 = Ip[(size_t)(odn + KD - 1) * HWp];
      eJ0 = Jp[(size_t)(odn + KD - 1) * HWp];
      lI0 = Ip[(size_t)odn * HWp];
      lJ0 = Jp[(size_t)odn * HWp];
      if (odn + 1 < oe) {
        eI1 = Ip[(size_t)(odn + KD) * HWp];
        eJ1 = Jp[(size_t)(odn + KD) * HWp];
        lI1 = Ip[(size_t)(odn + 1) * HWp];
        lJ1 = Jp[(size_t)(odn + 1) * HWp];
      }
    }
    // snapshot od into buffer 0
    sI += ceI0; sJ += ceJ0;
    sII += ceI0 * ceI0; sJJ += ceJ0 * ceJ0; sIJ += ceI0 * ceJ0;
    x4[0][p] = make_float4(sI, sJ, sII, sJJ); x1[0][p] = sIJ;
    sI -= clI0; sJ -= clJ0;
    sII -= clI0 * clI0; sJJ -= clJ0 * clJ0; sIJ -= clI0 * clJ0;
    if (two) {  // snapshot od+1 into buffer 1
      sI += ceI1; sJ += ceJ1;
      sII += ceI1 * ceI1; sJJ += ceJ1 * ceJ1; sIJ += ceI1 * ceJ1;
      x4[1][p] = make_float4(sI, sJ, sII, sJJ); x1[1][p] = sIJ;
      sI -= clI1; sJ -= clJ1;
      sII -= clI1 * clI1; sJJ -= clJ1 * clJ1; sIJ -= clI1 * clJ1;
    }
    asm volatile("s_waitcnt lgkmcnt(0)" ::: "memory");
    __builtin_amdgcn_s_barrier();       // B1: x[0] (and x[1]) visible
    // stage 1: a3[p] = x[p-1]+x[p]+x[p+1], both buffers
    {
      float4 m0 = x4[0][p - 1], m1 = x4[0][p], m2 = x4[0][p + 1];
      a4[0][p] = make_float4(m0.x + m1.x + m2.x, m0.y + m1.y + m2.y,
                             m0.z + m1.z + m2.z, m0.w + m1.w + m2.w);
      a1[0][p] = x1[0][p - 1] + x1[0][p] + x1[0][p + 1];
      if (pe >= 0) {
        float4 e0 = x4[0][pe - 1], e1 = x4[0][pe], e2 = x4[0][pe + 1];
        a4[0][pe] = make_float4(e0.x + e1.x + e2.x, e0.y + e1.y + e2.y,
                                e0.z + e1.z + e2.z, e0.w + e1.w + e2.w);
        a1[0][pe] = x1[0][pe - 1] + x1[0][pe] + x1[0][pe + 1];
      }
    }
    if (two) {
      float4 m0 = x4[1][p - 1], m1 = x4[1][p], m2 = x4[1][p + 1];
      a4[1][p] = make_float4(m0.x + m1.x + m2.x, m0.y + m1.y + m2.y,
                             m0.z + m1.z + m2.z, m0.w + m1.w + m2.w);
      a1[1][p] = x1[1][p - 1] + x1[1][p] + x1[1][p + 1];
      if (pe >= 0) {
        float4 e0 = x4[1][pe - 1], e1 = x4[1][pe], e2 = x4[1][pe + 1];
        a4[1][pe] = make_float4(e0.x + e1.x + e2.x, e0.y + e1.y + e2.y,
                                e0.z + e1.z + e2.z, e0.w + e1.w + e2.w);
        a1[1][pe] = x1[1][pe - 1] + x1[1][pe] + x1[1][pe + 1];
      }
    }
    asm volatile("s_waitcnt lgkmcnt(0)" ::: "memory");
    __builtin_amdgcn_s_barrier();       // B2: a[0] (and a[1]) visible
    // stage 2: S9 = a3[p-3]+a3[p]+a3[p+3]; SoA coalesced stores
    {
      float4 b0 = a4[0][p - 3], b1 = a4[0][p], b2 = a4[0][p + 3];
      const float r0 = b0.x + b1.x + b2.x;
      const float r1 = b0.y + b1.y + b2.y;
      const float r2 = b0.z + b1.z + b2.z;
      const float r3 = b0.w + b1.w + b2.w;
      const float r4 = a1[0][p - 3] + a1[0][p] + a1[0][p + 3];
      const size_t idx = (size_t)(od - od0) * HWp;
      wp0[idx] = bf16rne(r0) | (bf16rne(r1) << 16);
      wp1[idx] = bf16rne(r2) | (bf16rne(r3) << 16);
      wp2[idx] = bf16rne(r4);
    }
    if (two) {
      float4 b0 = a4[1][p - 3], b1 = a4[1][p], b2 = a4[1][p + 3];
      const float r0 = b0.x + b1.x + b2.x;
      const float r1 = b0.y + b1.y + b2.y;
      const float r2 = b0.z + b1.z + b2.z;
      const float r3 = b0.w + b1.w + b2.w;
      const float r4 = a1[1][p - 3] + a1[1][p] + a1[1][p + 3];
      const size_t idx = (size_t)(od + 1 - od0) * HWp;
      wp0[idx] = bf16rne(r0) | (bf16rne(r1) << 16);
      wp1[idx] = bf16rne(r2) | (bf16rne(r3) << 16);
      wp2[idx] = bf16rne(r4);
    }
    od += 2;
  }
}

// ---------------------------------------------------------------------------
// K2: 9-wide h box via fully-unrolled stream with 8-deep static ring
// (no subtract re-loads) + one-ahead prefetch; SoA coalesced loads;
// cc formula + loss reduction. Block: 192 threads = w-row,
// grid (od, h-chunk of 12, n).
__global__ __launch_bounds__(192)
void k_hcc(const unsigned* __restrict__ ws, float* __restrict__ cc,
           float* __restrict__ acc, int od0, int odcStride) {
  const int odi = blockIdx.x;
  const int od = od0 + odi;
  const int h0 = blockIdx.y * CH;
  const int n = blockIdx.z;
  const int w = threadIdx.x;
  const size_t PS = (size_t)2 * odcStride * HWp;    // plane stride (u32)
  const unsigned* b0 =
      ws + ((size_t)n * odcStride + odi) * HWp + w;
  const unsigned* b1 = b0 + PS;
  const unsigned* b2 = b0 + 2 * PS;
  float* ccp = cc + ((size_t)n * OD + od) * (size_t)HWp + w;

  float s0 = 0.f, s1 = 0.f, s2 = 0.f, s3 = 0.f, s4 = 0.f;
  float lsum = 0.f;
  unsigned h0r[8], h1r[8], h2r[8];

  // prefetch t=0 row
  unsigned v0 = 0u, v1 = 0u, v2 = 0u;
  {
    const int hin = h0 - 4;
    if (hin >= 0) {
      const size_t off = (size_t)hin * W;
      v0 = b0[off]; v1 = b1[off]; v2 = b2[off];
    }
  }
#pragma unroll
  for (int t = 0; t < CH + 8; ++t) {
    const unsigned c0 = v0, c1 = v1, c2 = v2;
    // prefetch next row
    if (t + 1 < CH + 8) {
      const int hn = h0 - 4 + t + 1;
      if (hn >= 0 && hn < H) {
        const size_t off = (size_t)hn * W;
        v0 = b0[off]; v1 = b1[off]; v2 = b2[off];
      } else { v0 = 0u; v1 = 0u; v2 = 0u; }
    }
    s0 += bf16tof(c0 & 0xffffu); s1 += bf16tof(c0 >> 16);
    s2 += bf16tof(c1 & 0xffffu); s3 += bf16tof(c1 >> 16);
    s4 += bf16tof(c2 & 0xffffu);
    if (t >= 8) {
      const int h = h0 + t - 8;
      const float cross = s4 - s0 * s1 * INV_WIN;
      const float vI = s2 - s0 * s0 * INV_WIN;
      const float vJ = s3 - s1 * s1 * INV_WIN;
      const float prod = vI * vJ;
      const float c = (prod > EPS_NZ) ? (cross * cross) / (prod + EPS_NZ)
                                      : 1.0f / (1.0f + EPS_NZ);
      ccp[(size_t)h * W] = c;
      lsum += c;
      const unsigned q0 = h0r[t & 7], q1 = h1r[t & 7], q2 = h2r[t & 7];
      s0 -= bf16tof(q0 & 0xffffu); s1 -= bf16tof(q0 >> 16);
      s2 -= bf16tof(q1 & 0xffffu); s3 -= bf16tof(q1 >> 16);
      s4 -= bf16tof(q2 & 0xffffu);
    }
    h0r[t & 7] = c0; h1r[t & 7] = c1; h2r[t & 7] = c2;  // static idx (unroll)
  }
  __shared__ float red[3];
#pragma unroll
  for (int off = 32; off > 0; off >>= 1) lsum += __shfl_xor(lsum, off, 64);
  if ((threadIdx.x & 63) == 0) red[threadIdx.x >> 6] = lsum;
  __syncthreads();
  if (threadIdx.x == 0) atomicAdd(acc + n, red[0] + red[1] + red[2]);
}

// ---------------------------------------------------------------------------
__global__ void k_fin(const float* __restrict__ acc, float* __restrict__ out) {
  if (threadIdx.x < N)
    out[threadIdx.x] = 1.0f - acc[threadIdx.x] * (1.0f / 2985984.0f);
}

// ---------------------------------------------------------------------------
extern "C" void kernel_launch(void* const* d_in, const int* in_sizes, int n_in,
                              void* d_out, int out_size, void* d_ws,
                              size_t ws_size, hipStream_t stream) {
  const float* I = (const float*)d_in[0];
  const float* J = (const float*)d_in[1];
  float* out = (float*)d_out;
  float* acc = (float*)d_ws;                       // 2 fp32 loss accumulators
  unsigned* planes = (unsigned*)((char*)d_ws + 256);

  hipMemsetAsync(d_ws, 0, 2 * sizeof(float), stream);

  // adaptive od-chunking: 12B/voxel across 3 planes, two n-slabs
  const size_t perOdPerN = (size_t)HWp * 12;       // 442368 B
  size_t avail = (ws_size > 256) ? (ws_size - 256) : 0;
  long long odcMax = (long long)(avail / (2 * perOdPerN));
  if (odcMax < 1) odcMax = 1;
  if (odcMax > OD) odcMax = OD;
  const int odc = (int)odcMax;                     // slab stride (od entries)

  float* ccOut = out + 2;
  for (int od0 = 0; od0 < OD; od0 += odc) {
    const int c = (odc < OD - od0) ? odc : (OD - od0);
    const int S = (c + ODPB - 1) / ODPB;
    hipLaunchKernelGGL(k_dw, dim3(H, S, N), dim3(192), 0, stream,
                       I, J, planes, od0, c, odc);
    hipLaunchKernelGGL(k_hcc, dim3(c, H / CH, N), dim3(192), 0, stream,
                       planes, ccOut, acc, od0, odc);
  }
  hipLaunchKernelGGL(k_fin, dim3(1), dim3(64), 0, stream, acc, out);
}

// Round 14
// 76.605 us; speedup vs baseline: 1.1859x; 1.1859x over previous
//
#include <hip/hip_runtime.h>

// LocalCrossCorrelation3D: I,J (2,1,96,192,192) fp32 -> (loss[2], cc[2,81,192,192])
// Window (16,9,9): depth valid (96->81), h/w zero-padded +-4.
// K1 = 2 h-rows per block, depth sliding sum (regs), two-stage 3+3 w-box in
// single-buffered float4 LDS (2 raw barriers/od; race-free: every LDS read
// is drained by the lgkmcnt(0) preceding the next barrier), 2-slot unrolled
// prefetch. ws = AoS uint3 (bf16-packed 12B/voxel, contiguous 768B/wave).
// K2 = h sliding box, full unroll + static 8-deep ring (round-12 known-good).

constexpr int N = 2, D = 96, H = 192, W = 192;
constexpr int OD = 81;            // D - 16 + 1
constexpr int KD = 16;
constexpr int HWp = H * W;        // 36864
constexpr float INV_WIN = 1.0f / 1296.0f;
constexpr float EPS_NZ = 3.0590232050182579e-07f;  // e^-15
constexpr int CH = 24;            // h-chunk per block in K2 (192/24 = 8)
constexpr int ODPB = 14;          // od-range per K1 block

__device__ __forceinline__ unsigned bf16rne(float f) {  // f32 -> bf16 bits (RNE)
  unsigned u = __float_as_uint(f);
  return (u + 0x7fffu + ((u >> 16) & 1u)) >> 16;
}
__device__ __forceinline__ float bf16tof(unsigned h) {  // bf16 bits -> f32
  return __uint_as_float(h << 16);
}

// ---------------------------------------------------------------------------
// K1. Block covers rows hA=2*bx, hB=hA+1. Per od: snapshot both rows' 5-ch
// sums to LDS, B1, 3-tap stage1 (both rows), B2, 3-tap stage2 + store.
// Hazard proof (single-buffered LDS, 2 barriers/od):
//  x-write(od+1) is after B2(od); all waves' x-reads(od) drained by the
//  lgkmcnt(0) each wave executes before B2(od)  -> safe.
//  a-write(od+1) is after B1(od+1); all waves' a-reads(od) feed VALU adds
//  (compiler waits) before the x-snapshot/lgkmcnt(0)/B1(od+1)  -> safe.
// ws layout: [n][odi][h][w] x 3 uints (bf16 pairs: (s0,s1),(s2,s3),(s4,_)).
__global__ __launch_bounds__(192)
void k_dw(const float* __restrict__ I, const float* __restrict__ J,
          unsigned* __restrict__ ws, int od0, int c, int odcStride) {
  const int hA = 2 * blockIdx.x, hB = hA + 1;
  const int n = blockIdx.z;
  const int os = od0 + blockIdx.y * ODPB;
  int oe = od0 + c; if (os + ODPB < oe) oe = os + ODPB;
  if (os >= oe) return;
  const int w = threadIdx.x;

  __shared__ float4 xA4[W + 8]; __shared__ float xA1[W + 8];
  __shared__ float4 xB4[W + 8]; __shared__ float xB1[W + 8];
  __shared__ float4 aA4[W + 8]; __shared__ float aA1[W + 8];
  __shared__ float4 aB4[W + 8]; __shared__ float aB1[W + 8];

  if (w < 4) {
    xA4[w] = make_float4(0.f,0.f,0.f,0.f); xA1[w] = 0.f;
    xB4[w] = make_float4(0.f,0.f,0.f,0.f); xB1[w] = 0.f;
  }
  if (w >= W - 4) {
    xA4[w + 8] = make_float4(0.f,0.f,0.f,0.f); xA1[w + 8] = 0.f;
    xB4[w + 8] = make_float4(0.f,0.f,0.f,0.f); xB1[w + 8] = 0.f;
  }
  __syncthreads();   // one safe barrier before the pipelined loop

  const size_t baseA = ((size_t)n * D * H + hA) * (size_t)W + w;
  const float* IpA = I + baseA;
  const float* JpA = J + baseA;
  const float* IpB = IpA + W;
  const float* JpB = JpA + W;
  unsigned* wbA = ws + ((size_t)n * odcStride * HWp + (size_t)hA * W + w) * 3;
  unsigned* wbB = wbA + (size_t)W * 3;

  int pe = -1;                        // extra halo position for stage1
  if (w < 3) pe = w + 1;
  else if (w >= W - 3) pe = w + 7;
  const int p = 4 + w;

  // warm-up: accumulate slices [os, os+KD-2] (15 slices), both rows
  float sIA=0.f,sJA=0.f,sIIA=0.f,sJJA=0.f,sIJA=0.f;
  float sIB=0.f,sJB=0.f,sIIB=0.f,sJJB=0.f,sIJB=0.f;
  for (int d = os; d < os + KD - 1; ++d) {
    const float ia = IpA[(size_t)d * HWp], ja = JpA[(size_t)d * HWp];
    const float ib = IpB[(size_t)d * HWp], jb = JpB[(size_t)d * HWp];
    sIA += ia; sJA += ja; sIIA += ia*ia; sJJA += ja*ja; sIJA += ia*ja;
    sIB += ib; sJB += jb; sIIB += ib*ib; sJJB += jb*jb; sIJB += ib*jb;
  }

#define ISSUE(eIA,eJA,lIA,lJA,eIB,eJB,lIB,lJB, ODX)                          \
  { const int _o = (ODX);                                                    \
    eIA = IpA[(size_t)(_o + KD - 1) * HWp];                                  \
    eJA = JpA[(size_t)(_o + KD - 1) * HWp];                                  \
    lIA = IpA[(size_t)_o * HWp];                                             \
    lJA = JpA[(size_t)_o * HWp];                                             \
    eIB = IpB[(size_t)(_o + KD - 1) * HWp];                                  \
    eJB = JpB[(size_t)(_o + KD - 1) * HWp];                                  \
    lIB = IpB[(size_t)_o * HWp];                                             \
    lJB = JpB[(size_t)_o * HWp]; }

#define COMPUTE(ODX, eIA,eJA,lIA,lJA,eIB,eJB,lIB,lJB)                        \
  { const int _od = (ODX);                                                   \
    sIA += eIA; sJA += eJA; sIIA += eIA*eIA; sJJA += eJA*eJA; sIJA += eIA*eJA;\
    xA4[p] = make_float4(sIA, sJA, sIIA, sJJA); xA1[p] = sIJA;               \
    sIA -= lIA; sJA -= lJA; sIIA -= lIA*lIA; sJJA -= lJA*lJA; sIJA -= lIA*lJA;\
    sIB += eIB; sJB += eJB; sIIB += eIB*eIB; sJJB += eJB*eJB; sIJB += eIB*eJB;\
    xB4[p] = make_float4(sIB, sJB, sIIB, sJJB); xB1[p] = sIJB;               \
    sIB -= lIB; sJB -= lJB; sIIB -= lIB*lIB; sJJB -= lJB*lJB; sIJB -= lIB*lJB;\
    asm volatile("s_waitcnt lgkmcnt(0)" ::: "memory");                       \
    __builtin_amdgcn_s_barrier();      /* B1: x visible */                   \
    { float4 m0 = xA4[p-1], m1 = xA4[p], m2 = xA4[p+1];                      \
      aA4[p] = make_float4(m0.x+m1.x+m2.x, m0.y+m1.y+m2.y,                   \
                           m0.z+m1.z+m2.z, m0.w+m1.w+m2.w);                  \
      aA1[p] = xA1[p-1] + xA1[p] + xA1[p+1];                                 \
      float4 n0 = xB4[p-1], n1 = xB4[p], n2 = xB4[p+1];                      \
      aB4[p] = make_float4(n0.x+n1.x+n2.x, n0.y+n1.y+n2.y,                   \
                           n0.z+n1.z+n2.z, n0.w+n1.w+n2.w);                  \
      aB1[p] = xB1[p-1] + xB1[p] + xB1[p+1];                                 \
      if (pe >= 0) {                                                         \
        float4 e0 = xA4[pe-1], e1 = xA4[pe], e2 = xA4[pe+1];                 \
        aA4[pe] = make_float4(e0.x+e1.x+e2.x, e0.y+e1.y+e2.y,                \
                              e0.z+e1.z+e2.z, e0.w+e1.w+e2.w);               \
        aA1[pe] = xA1[pe-1] + xA1[pe] + xA1[pe+1];                           \
        float4 f0 = xB4[pe-1], f1 = xB4[pe], f2 = xB4[pe+1];                 \
        aB4[pe] = make_float4(f0.x+f1.x+f2.x, f0.y+f1.y+f2.y,                \
                              f0.z+f1.z+f2.z, f0.w+f1.w+f2.w);               \
        aB1[pe] = xB1[pe-1] + xB1[pe] + xB1[pe+1];                           \
      } }                                                                    \
    asm volatile("s_waitcnt lgkmcnt(0)" ::: "memory");                       \
    __builtin_amdgcn_s_barrier();      /* B2: a visible */                   \
    { float4 b0 = aA4[p-3], b1 = aA4[p], b2 = aA4[p+3];                      \
      const float r0 = b0.x+b1.x+b2.x, r1 = b0.y+b1.y+b2.y;                  \
      const float r2 = b0.z+b1.z+b2.z, r3 = b0.w+b1.w+b2.w;                  \
      const float r4 = aA1[p-3] + aA1[p] + aA1[p+3];                         \
      unsigned* o = wbA + (size_t)(_od - od0) * HWp * 3;                     \
      *(uint3*)o = make_uint3(bf16rne(r0) | (bf16rne(r1) << 16),             \
                              bf16rne(r2) | (bf16rne(r3) << 16),             \
                              bf16rne(r4));                                  \
      float4 c0 = aB4[p-3], c1 = aB4[p], c2 = aB4[p+3];                      \
      const float q0 = c0.x+c1.x+c2.x, q1 = c0.y+c1.y+c2.y;                  \
      const float q2 = c0.z+c1.z+c2.z, q3 = c0.w+c1.w+c2.w;                  \
      const float q4 = aB1[p-3] + aB1[p] + aB1[p+3];                         \
      unsigned* o2 = wbB + (size_t)(_od - od0) * HWp * 3;                    \
      *(uint3*)o2 = make_uint3(bf16rne(q0) | (bf16rne(q1) << 16),            \
                               bf16rne(q2) | (bf16rne(q3) << 16),            \
                               bf16rne(q4)); } }

  // 2-slot unrolled prefetch (named regs; no slot copies)
  float eIA0=0,eJA0=0,lIA0=0,lJA0=0,eIB0=0,eJB0=0,lIB0=0,lJB0=0;
  float eIA1=0,eJA1=0,lIA1=0,lJA1=0,eIB1=0,eJB1=0,lIB1=0,lJB1=0;
  ISSUE(eIA0,eJA0,lIA0,lJA0,eIB0,eJB0,lIB0,lJB0, os)
  if (os + 1 < oe) ISSUE(eIA1,eJA1,lIA1,lJA1,eIB1,eJB1,lIB1,lJB1, os + 1)

  for (int od = os; od < oe; od += 2) {
    COMPUTE(od, eIA0,eJA0,lIA0,lJA0,eIB0,eJB0,lIB0,lJB0)
    if (od + 2 < oe) ISSUE(eIA0,eJA0,lIA0,lJA0,eIB0,eJB0,lIB0,lJB0, od + 2)
    if (od + 1 < oe) {
      COMPUTE(od + 1, eIA1,eJA1,lIA1,lJA1,eIB1,eJB1,lIB1,lJB1)
      if (od + 3 < oe) ISSUE(eIA1,eJA1,lIA1,lJA1,eIB1,eJB1,lIB1,lJB1, od + 3)
    }
  }
#undef ISSUE
#undef COMPUTE
}

// ---------------------------------------------------------------------------
// K2: 9-wide h box via fully-unrolled stream with an 8-deep static ring
// (no subtract re-loads; full unroll -> static indices + deep load pipelining)
// + one-ahead prefetch; cc formula + loss reduction.
// Block: 192 threads = w-row, grid (od, h-chunk of 24, n).
__global__ __launch_bounds__(192)
void k_hcc(const unsigned* __restrict__ ws, float* __restrict__ cc,
           float* __restrict__ acc, int od0, int odcStride) {
  const int odi = blockIdx.x;
  const int od = od0 + odi;
  const int h0 = blockIdx.y * CH;
  const int n = blockIdx.z;
  const int w = threadIdx.x;
  const unsigned* base =
      ws + ((size_t)n * odcStride * HWp + (size_t)odi * HWp + w) * 3;
  float* ccp = cc + ((size_t)n * OD + od) * (size_t)HWp + w;

  float s0 = 0.f, s1 = 0.f, s2 = 0.f, s3 = 0.f, s4 = 0.f;
  float lsum = 0.f;
  uint3 hist[8];
  const uint3 z3 = make_uint3(0u, 0u, 0u);

  // prefetch t=0 row
  uint3 vN = z3;
  {
    const int hin = h0 - 4;
    if (hin >= 0) vN = *(const uint3*)(base + (size_t)hin * W * 3);
  }
#pragma unroll
  for (int t = 0; t < CH + 8; ++t) {
    const uint3 v = vN;
    // prefetch next row
    if (t + 1 < CH + 8) {
      const int hn = h0 - 4 + t + 1;
      vN = (hn >= 0 && hn < H) ? *(const uint3*)(base + (size_t)hn * W * 3) : z3;
    }
    s0 += bf16tof(v.x & 0xffffu); s1 += bf16tof(v.x >> 16);
    s2 += bf16tof(v.y & 0xffffu); s3 += bf16tof(v.y >> 16);
    s4 += bf16tof(v.z & 0xffffu);
    if (t >= 8) {
      const int h = h0 + t - 8;
      const float cross = s4 - s0 * s1 * INV_WIN;
      const float vI = s2 - s0 * s0 * INV_WIN;
      const float vJ = s3 - s1 * s1 * INV_WIN;
      const float prod = vI * vJ;
      const float c = (prod > EPS_NZ) ? (cross * cross) / (prod + EPS_NZ)
                                      : 1.0f / (1.0f + EPS_NZ);
      ccp[(size_t)h * W] = c;
      lsum += c;
      const uint3 q = hist[t & 7];       // row that entered 8 steps ago
      s0 -= bf16tof(q.x & 0xffffu); s1 -= bf16tof(q.x >> 16);
      s2 -= bf16tof(q.y & 0xffffu); s3 -= bf16tof(q.y >> 16);
      s4 -= bf16tof(q.z & 0xffffu);
    }
    hist[t & 7] = v;                     // static index (full unroll)
  }
  __shared__ float red[3];
#pragma unroll
  for (int off = 32; off > 0; off >>= 1) lsum += __shfl_xor(lsum, off, 64);
  if ((threadIdx.x & 63) == 0) red[threadIdx.x >> 6] = lsum;
  __syncthreads();
  if (threadIdx.x == 0) atomicAdd(acc + n, red[0] + red[1] + red[2]);
}

// ---------------------------------------------------------------------------
__global__ void k_fin(const float* __restrict__ acc, float* __restrict__ out) {
  if (threadIdx.x < N)
    out[threadIdx.x] = 1.0f - acc[threadIdx.x] * (1.0f / 2985984.0f);
}

// ---------------------------------------------------------------------------
extern "C" void kernel_launch(void* const* d_in, const int* in_sizes, int n_in,
                              void* d_out, int out_size, void* d_ws,
                              size_t ws_size, hipStream_t stream) {
  const float* I = (const float*)d_in[0];
  const float* J = (const float*)d_in[1];
  float* out = (float*)d_out;
  float* acc = (float*)d_ws;                       // 2 fp32 loss accumulators
  unsigned* planes = (unsigned*)((char*)d_ws + 256);

  hipMemsetAsync(d_ws, 0, 2 * sizeof(float), stream);

  // adaptive od-chunking: packed voxel = 12B, two n-slabs
  const size_t perOdPerN = (size_t)HWp * 12;       // 442368 B
  size_t avail = (ws_size > 256) ? (ws_size - 256) : 0;
  long long odcMax = (long long)(avail / (2 * perOdPerN));
  if (odcMax < 1) odcMax = 1;
  if (odcMax > OD) odcMax = OD;
  const int odc = (int)odcMax;                     // slab stride (od entries)

  float* ccOut = out + 2;
  for (int od0 = 0; od0 < OD; od0 += odc) {
    const int c = (odc < OD - od0) ? odc : (OD - od0);
    const int S = (c + ODPB - 1) / ODPB;
    hipLaunchKernelGGL(k_dw, dim3(H / 2, S, N), dim3(192), 0, stream,
                       I, J, planes, od0, c, odc);
    hipLaunchKernelGGL(k_hcc, dim3(c, H / CH, N), dim3(192), 0, stream,
                       planes, ccOut, acc, od0, odc);
  }
  hipLaunchKernelGGL(k_fin, dim3(1), dim3(64), 0, stream, acc, out);
}

// Round 15
// 64.497 us; speedup vs baseline: 1.4085x; 1.1877x over previous
//
#include <hip/hip_runtime.h>

// LocalCrossCorrelation3D: I,J (2,1,96,192,192) fp32 -> (loss[2], cc[2,81,192,192])
// Window (16,9,9): depth valid (96->81), h/w zero-padded +-4.
// K1 = depth sliding sum (regs, prefetched) + two-stage 3+3 w-box in float4
// LDS, two od-outputs per barrier round, raw barriers (round-10 known-good).
// K2 = h sliding box, full unroll + static 8-deep ring; loss partials go to
// 64 SPREAD accumulator slots (atomic same-line serialization fix).
// K3 = shuffle-reduce of the 64 slots.

constexpr int N = 2, D = 96, H = 192, W = 192;
constexpr int OD = 81;            // D - 16 + 1
constexpr int KD = 16;
constexpr int HWp = H * W;        // 36864
constexpr float INV_WIN = 1.0f / 1296.0f;
constexpr float EPS_NZ = 3.0590232050182579e-07f;  // e^-15
constexpr int CH = 24;            // h-chunk per block in K2 (192/24 = 8)
constexpr int ODPB = 14;          // od-range per K1 block (9 blocks/CU)

__device__ __forceinline__ unsigned bf16rne(float f) {  // f32 -> bf16 bits (RNE)
  unsigned u = __float_as_uint(f);
  return (u + 0x7fffu + ((u >> 16) & 1u)) >> 16;
}
__device__ __forceinline__ float bf16tof(unsigned h) {  // bf16 bits -> f32
  return __uint_as_float(h << 16);
}

// ---------------------------------------------------------------------------
// K1. Per (n,h) row, stream depth with running 5-ch sums; snapshots for od
// and od+1 go to LDS buffer sets 0/1; one {B1,stage1x2,B2,stage2x2} round
// serves both. Entering/leaving slices for the NEXT pair prefetched during
// the current round. ws layout: [n][odi][h][w] x 3 uints (bf16 pairs).
__global__ __launch_bounds__(192)
void k_dw(const float* __restrict__ I, const float* __restrict__ J,
          unsigned* __restrict__ ws, int od0, int c, int odcStride) {
  const int h = blockIdx.x;
  const int n = blockIdx.z;
  const int os = od0 + blockIdx.y * ODPB;
  int oe = od0 + c; if (os + ODPB < oe) oe = os + ODPB;
  if (os >= oe) return;
  const int w = threadIdx.x;

  __shared__ float4 x4[2][W + 8];
  __shared__ float  x1[2][W + 8];
  __shared__ float4 a4[2][W + 8];
  __shared__ float  a1[2][W + 8];

  if (w < 4) {
    x4[0][w] = make_float4(0.f,0.f,0.f,0.f); x1[0][w] = 0.f;
    x4[1][w] = make_float4(0.f,0.f,0.f,0.f); x1[1][w] = 0.f;
  }
  if (w >= W - 4) {
    x4[0][w + 8] = make_float4(0.f,0.f,0.f,0.f); x1[0][w + 8] = 0.f;
    x4[1][w + 8] = make_float4(0.f,0.f,0.f,0.f); x1[1][w + 8] = 0.f;
  }
  __syncthreads();   // one safe barrier before the pipelined loop

  const size_t colBase = ((size_t)n * D * H + h) * (size_t)W + w;
  const float* Ip = I + colBase;
  const float* Jp = J + colBase;
  unsigned* wbase = ws + ((size_t)n * odcStride * HWp + (size_t)h * W + w) * 3;

  // extra a3 position for halo coverage (pe in 1..3 and 196..198)
  int pe = -1;
  if (w < 3) pe = w + 1;
  else if (w >= W - 3) pe = w + 7;
  const int p = 4 + w;

  // warm-up: accumulate slices [os, os+KD-2] (15 slices)
  float sI = 0.f, sJ = 0.f, sII = 0.f, sJJ = 0.f, sIJ = 0.f;
  for (int d = os; d < os + KD - 1; ++d) {
    const float iv = Ip[(size_t)d * HWp];
    const float jv = Jp[(size_t)d * HWp];
    sI += iv; sJ += jv;
    sII += iv * iv; sJJ += jv * jv; sIJ += iv * jv;
  }

  // prefetch first pair: entering od+15 / od+16, leaving od / od+1
  int od = os;
  float eI0 = Ip[(size_t)(od + KD - 1) * HWp];
  float eJ0 = Jp[(size_t)(od + KD - 1) * HWp];
  float lI0 = Ip[(size_t)od * HWp];
  float lJ0 = Jp[(size_t)od * HWp];
  float eI1 = 0.f, eJ1 = 0.f, lI1 = 0.f, lJ1 = 0.f;
  if (od + 1 < oe) {
    eI1 = Ip[(size_t)(od + KD) * HWp];
    eJ1 = Jp[(size_t)(od + KD) * HWp];
    lI1 = Ip[(size_t)(od + 1) * HWp];
    lJ1 = Jp[(size_t)(od + 1) * HWp];
  }

  while (od < oe) {
    const bool two = (od + 1 < oe);
    const float ceI0 = eI0, ceJ0 = eJ0, clI0 = lI0, clJ0 = lJ0;
    const float ceI1 = eI1, ceJ1 = eJ1, clI1 = lI1, clJ1 = lJ1;
    // prefetch next pair (issued now, awaited next iteration)
    const int odn = od + 2;
    if (odn < oe) {
      eI0 = Ip[(size_t)(odn + KD - 1) * HWp];
      eJ0 = Jp[(size_t)(odn + KD - 1) * HWp];
      lI0 = Ip[(size_t)odn * HWp];
      lJ0 = Jp[(size_t)odn * HWp];
      if (odn + 1 < oe) {
        eI1 = Ip[(size_t)(odn + KD) * HWp];
        eJ1 = Jp[(size_t)(odn + KD) * HWp];
        lI1 = Ip[(size_t)(odn + 1) * HWp];
        lJ1 = Jp[(size_t)(odn + 1) * HWp];
      }
    }
    // snapshot od into buffer 0
    sI += ceI0; sJ += ceJ0;
    sII += ceI0 * ceI0; sJJ += ceJ0 * ceJ0; sIJ += ceI0 * ceJ0;
    x4[0][p] = make_float4(sI, sJ, sII, sJJ); x1[0][p] = sIJ;
    sI -= clI0; sJ -= clJ0;
    sII -= clI0 * clI0; sJJ -= clJ0 * clJ0; sIJ -= clI0 * clJ0;
    if (two) {  // snapshot od+1 into buffer 1
      sI += ceI1; sJ += ceJ1;
      sII += ceI1 * ceI1; sJJ += ceJ1 * ceJ1; sIJ += ceI1 * ceJ1;
      x4[1][p] = make_float4(sI, sJ, sII, sJJ); x1[1][p] = sIJ;
      sI -= clI1; sJ -= clJ1;
      sII -= clI1 * clI1; sJJ -= clJ1 * clJ1; sIJ -= clI1 * clJ1;
    }
    asm volatile("s_waitcnt lgkmcnt(0)" ::: "memory");
    __builtin_amdgcn_s_barrier();       // B1: x[0] (and x[1]) visible
    // stage 1: a3[p] = x[p-1]+x[p]+x[p+1], both buffers
    {
      float4 m0 = x4[0][p - 1], m1 = x4[0][p], m2 = x4[0][p + 1];
      a4[0][p] = make_float4(m0.x + m1.x + m2.x, m0.y + m1.y + m2.y,
                             m0.z + m1.z + m2.z, m0.w + m1.w + m2.w);
      a1[0][p] = x1[0][p - 1] + x1[0][p] + x1[0][p + 1];
      if (pe >= 0) {
        float4 e0 = x4[0][pe - 1], e1 = x4[0][pe], e2 = x4[0][pe + 1];
        a4[0][pe] = make_float4(e0.x + e1.x + e2.x, e0.y + e1.y + e2.y,
                                e0.z + e1.z + e2.z, e0.w + e1.w + e2.w);
        a1[0][pe] = x1[0][pe - 1] + x1[0][pe] + x1[0][pe + 1];
      }
    }
    if (two) {
      float4 m0 = x4[1][p - 1], m1 = x4[1][p], m2 = x4[1][p + 1];
      a4[1][p] = make_float4(m0.x + m1.x + m2.x, m0.y + m1.y + m2.y,
                             m0.z + m1.z + m2.z, m0.w + m1.w + m2.w);
      a1[1][p] = x1[1][p - 1] + x1[1][p] + x1[1][p + 1];
      if (pe >= 0) {
        float4 e0 = x4[1][pe - 1], e1 = x4[1][pe], e2 = x4[1][pe + 1];
        a4[1][pe] = make_float4(e0.x + e1.x + e2.x, e0.y + e1.y + e2.y,
                                e0.z + e1.z + e2.z, e0.w + e1.w + e2.w);
        a1[1][pe] = x1[1][pe - 1] + x1[1][pe] + x1[1][pe + 1];
      }
    }
    asm volatile("s_waitcnt lgkmcnt(0)" ::: "memory");
    __builtin_amdgcn_s_barrier();       // B2: a[0] (and a[1]) visible
    // stage 2: S9 = a3[p-3]+a3[p]+a3[p+3]; store
    {
      float4 b0 = a4[0][p - 3], b1 = a4[0][p], b2 = a4[0][p + 3];
      const float r0 = b0.x + b1.x + b2.x;
      const float r1 = b0.y + b1.y + b2.y;
      const float r2 = b0.z + b1.z + b2.z;
      const float r3 = b0.w + b1.w + b2.w;
      const float r4 = a1[0][p - 3] + a1[0][p] + a1[0][p + 3];
      unsigned* o = wbase + (size_t)(od - od0) * HWp * 3;
      *(uint3*)o = make_uint3(bf16rne(r0) | (bf16rne(r1) << 16),
                              bf16rne(r2) | (bf16rne(r3) << 16),
                              bf16rne(r4));
    }
    if (two) {
      float4 b0 = a4[1][p - 3], b1 = a4[1][p], b2 = a4[1][p + 3];
      const float r0 = b0.x + b1.x + b2.x;
      const float r1 = b0.y + b1.y + b2.y;
      const float r2 = b0.z + b1.z + b2.z;
      const float r3 = b0.w + b1.w + b2.w;
      const float r4 = a1[1][p - 3] + a1[1][p] + a1[1][p + 3];
      unsigned* o = wbase + (size_t)(od + 1 - od0) * HWp * 3;
      *(uint3*)o = make_uint3(bf16rne(r0) | (bf16rne(r1) << 16),
                              bf16rne(r2) | (bf16rne(r3) << 16),
                              bf16rne(r4));
    }
    od += 2;
  }
}

// ---------------------------------------------------------------------------
// K2: 9-wide h box via fully-unrolled stream with an 8-deep static ring
// (no subtract re-loads) + one-ahead prefetch; cc formula + loss reduction.
// Loss partial -> one of 32 spread slots per batch (breaks same-cache-line
// atomic serialization across the 1296 blocks).
// Block: 192 threads = w-row, grid (od, h-chunk of 24, n).
__global__ __launch_bounds__(192)
void k_hcc(const unsigned* __restrict__ ws, float* __restrict__ cc,
           float* __restrict__ acc, int od0, int odcStride) {
  const int odi = blockIdx.x;
  const int od = od0 + odi;
  const int h0 = blockIdx.y * CH;
  const int n = blockIdx.z;
  const int w = threadIdx.x;
  const unsigned* base =
      ws + ((size_t)n * odcStride * HWp + (size_t)odi * HWp + w) * 3;
  float* ccp = cc + ((size_t)n * OD + od) * (size_t)HWp + w;

  float s0 = 0.f, s1 = 0.f, s2 = 0.f, s3 = 0.f, s4 = 0.f;
  float lsum = 0.f;
  uint3 hist[8];
  const uint3 z3 = make_uint3(0u, 0u, 0u);

  // prefetch t=0 row
  uint3 vN = z3;
  {
    const int hin = h0 - 4;
    if (hin >= 0) vN = *(const uint3*)(base + (size_t)hin * W * 3);
  }
#pragma unroll
  for (int t = 0; t < CH + 8; ++t) {
    const uint3 v = vN;
    // prefetch next row
    if (t + 1 < CH + 8) {
      const int hn = h0 - 4 + t + 1;
      vN = (hn >= 0 && hn < H) ? *(const uint3*)(base + (size_t)hn * W * 3) : z3;
    }
    s0 += bf16tof(v.x & 0xffffu); s1 += bf16tof(v.x >> 16);
    s2 += bf16tof(v.y & 0xffffu); s3 += bf16tof(v.y >> 16);
    s4 += bf16tof(v.z & 0xffffu);
    if (t >= 8) {
      const int h = h0 + t - 8;
      const float cross = s4 - s0 * s1 * INV_WIN;
      const float vI = s2 - s0 * s0 * INV_WIN;
      const float vJ = s3 - s1 * s1 * INV_WIN;
      const float prod = vI * vJ;
      const float c = (prod > EPS_NZ) ? (cross * cross) / (prod + EPS_NZ)
                                      : 1.0f / (1.0f + EPS_NZ);
      ccp[(size_t)h * W] = c;
      lsum += c;
      const uint3 q = hist[t & 7];       // row that entered 8 steps ago
      s0 -= bf16tof(q.x & 0xffffu); s1 -= bf16tof(q.x >> 16);
      s2 -= bf16tof(q.y & 0xffffu); s3 -= bf16tof(q.y >> 16);
      s4 -= bf16tof(q.z & 0xffffu);
    }
    hist[t & 7] = v;                     // static index (full unroll)
  }
  __shared__ float red[3];
#pragma unroll
  for (int off = 32; off > 0; off >>= 1) lsum += __shfl_xor(lsum, off, 64);
  if ((threadIdx.x & 63) == 0) red[threadIdx.x >> 6] = lsum;
  __syncthreads();
  if (threadIdx.x == 0)
    atomicAdd(acc + n * 32 + (odi & 31), red[0] + red[1] + red[2]);
}

// ---------------------------------------------------------------------------
// K3: reduce the 64 spread slots (32 per batch) -> loss.
__global__ void k_fin(const float* __restrict__ acc, float* __restrict__ out) {
  const int t = threadIdx.x;            // 64 threads
  float v = acc[t];                     // slots [n*32 + k]
#pragma unroll
  for (int off = 16; off > 0; off >>= 1) v += __shfl_xor(v, off, 32);
  if (t == 0)  out[0] = 1.0f - v * (1.0f / 2985984.0f);
  if (t == 32) out[1] = 1.0f - v * (1.0f / 2985984.0f);
}

// ---------------------------------------------------------------------------
extern "C" void kernel_launch(void* const* d_in, const int* in_sizes, int n_in,
                              void* d_out, int out_size, void* d_ws,
                              size_t ws_size, hipStream_t stream) {
  const float* I = (const float*)d_in[0];
  const float* J = (const float*)d_in[1];
  float* out = (float*)d_out;
  float* acc = (float*)d_ws;                       // 64 fp32 spread slots
  unsigned* planes = (unsigned*)((char*)d_ws + 256);

  hipMemsetAsync(d_ws, 0, 64 * sizeof(float), stream);

  // adaptive od-chunking: packed voxel = 12B, two n-slabs
  const size_t perOdPerN = (size_t)HWp * 12;       // 442368 B
  size_t avail = (ws_size > 256) ? (ws_size - 256) : 0;
  long long odcMax = (long long)(avail / (2 * perOdPerN));
  if (odcMax < 1) odcMax = 1;
  if (odcMax > OD) odcMax = OD;
  const int odc = (int)odcMax;                     // slab stride (od entries)

  float* ccOut = out + 2;
  for (int od0 = 0; od0 < OD; od0 += odc) {
    const int c = (odc < OD - od0) ? odc : (OD - od0);
    const int S = (c + ODPB - 1) / ODPB;
    hipLaunchKernelGGL(k_dw, dim3(H, S, N), dim3(192), 0, stream,
                       I, J, planes, od0, c, odc);
    hipLaunchKernelGGL(k_hcc, dim3(c, H / CH, N), dim3(192), 0, stream,
                       planes, ccOut, acc, od0, odc);
  }
  hipLaunchKernelGGL(k_fin, dim3(1), dim3(64), 0, stream, acc, out);
}